// Round 4
// baseline (4900.158 us; speedup 1.0000x reference)
//
#include <hip/hip_runtime.h>
#include <hip/hip_fp16.h>
#include <math.h>

#define N_NODES 100000
#define N_EDGES 1600000
#define IN_F    128
#define OUT_F   64
#define NB      ((N_NODES + 255) / 256)   // 391
#define EB      (N_EDGES / 256)           // 6250 (exact)
#define K_BKT   16
#define BKT_NODES 6250                    // N_NODES / K_BKT exact
#define BPB     64                        // phase-2 blocks per bucket

// ---------------- workspace layout (4-byte units) ----------------
// fth      : N_NODES*OUT_F/2  (fp16 projected features, 12.8 MB)
// staging  : N_EDGES uint2    (bucketed (src,dst) pairs, 12.8 MB)
// edge_src : N_EDGES          (final CSR src ids, 6.4 MB)
// deg      : N_NODES          (degree -> per-node scatter cursor)
// row_start: N_NODES+1
// bsum/boff: NB each
// bstart   : K_BKT+1 ; bcursor : K_BKT

__global__ __launch_bounds__(256) void init_kernel(int* __restrict__ deg) {
    int i = blockIdx.x * 256 + threadIdx.x;
    if (i < N_NODES) deg[i] = 0;
}

// blocks [0,NB): ft = feat @ W, stored fp16; blocks [NB,NB+EB): degree count
__global__ __launch_bounds__(256) void linear_count_kernel(const float* __restrict__ feat,
                                                           const float* __restrict__ W,
                                                           __half* __restrict__ fth,
                                                           const int* __restrict__ dst,
                                                           int* __restrict__ deg) {
    if (blockIdx.x >= NB) {
        int e = (blockIdx.x - NB) * 256 + threadIdx.x;
        if (e < N_EDGES) atomicAdd(&deg[dst[e]], 1);
        return;
    }
    __shared__ float4 Wl[IN_F * OUT_F / 4];   // 32 KB
    const float4* W4 = (const float4*)W;
    for (int i = threadIdx.x; i < IN_F * OUT_F / 4; i += 256) Wl[i] = W4[i];
    __syncthreads();

    int row = blockIdx.x * 256 + threadIdx.x;
    if (row >= N_NODES) return;
    const float4* fr = (const float4*)(feat + (size_t)row * IN_F);

    float acc[OUT_F];
#pragma unroll
    for (int c = 0; c < OUT_F; ++c) acc[c] = 0.f;

    for (int kc = 0; kc < IN_F / 4; ++kc) {
        float4 f = fr[kc];
        const float4* w0 = &Wl[(4 * kc + 0) * (OUT_F / 4)];
        const float4* w1 = &Wl[(4 * kc + 1) * (OUT_F / 4)];
        const float4* w2 = &Wl[(4 * kc + 2) * (OUT_F / 4)];
        const float4* w3 = &Wl[(4 * kc + 3) * (OUT_F / 4)];
#pragma unroll
        for (int c4 = 0; c4 < OUT_F / 4; ++c4) {
            float4 a0 = w0[c4], a1 = w1[c4], a2 = w2[c4], a3 = w3[c4];
            acc[4 * c4 + 0] += f.x * a0.x + f.y * a1.x + f.z * a2.x + f.w * a3.x;
            acc[4 * c4 + 1] += f.x * a0.y + f.y * a1.y + f.z * a2.y + f.w * a3.y;
            acc[4 * c4 + 2] += f.x * a0.z + f.y * a1.z + f.z * a2.z + f.w * a3.z;
            acc[4 * c4 + 3] += f.x * a0.w + f.y * a1.w + f.z * a2.w + f.w * a3.w;
        }
    }
    // pack 64 fp16 -> 128 B -> 8 float4 stores
    float4* o = (float4*)(fth + (size_t)row * OUT_F);
#pragma unroll
    for (int q = 0; q < 8; ++q) {
        unsigned u[4];
#pragma unroll
        for (int j = 0; j < 4; ++j) {
            int c = q * 8 + j * 2;
            __half h0 = __float2half_rn(acc[c]);
            __half h1 = __float2half_rn(acc[c + 1]);
            u[j] = (unsigned)__half_as_ushort(h0) | ((unsigned)__half_as_ushort(h1) << 16);
        }
        o[q] = make_float4(__uint_as_float(u[0]), __uint_as_float(u[1]),
                           __uint_as_float(u[2]), __uint_as_float(u[3]));
    }
}

__global__ __launch_bounds__(256) void blockreduce_kernel(const int* __restrict__ deg,
                                                          int* __restrict__ bsum) {
    __shared__ int sb[256];
    int t = threadIdx.x, i = blockIdx.x * 256 + t;
    sb[t] = (i < N_NODES) ? deg[i] : 0;
    __syncthreads();
    for (int off = 128; off > 0; off >>= 1) {
        if (t < off) sb[t] += sb[t + off];
        __syncthreads();
    }
    if (t == 0) bsum[blockIdx.x] = sb[0];
}

__global__ __launch_bounds__(512) void scanbsum_kernel(const int* __restrict__ bsum,
                                                       int* __restrict__ boff,
                                                       int* __restrict__ row_start,
                                                       int* __restrict__ bstart) {
    __shared__ int sb[512];
    int t = threadIdx.x;
    int v = (t < NB) ? bsum[t] : 0;
    sb[t] = v;
    __syncthreads();
    for (int off = 1; off < 512; off <<= 1) {
        int add = (t >= off) ? sb[t - off] : 0;
        __syncthreads();
        sb[t] += add;
        __syncthreads();
    }
    if (t < NB) boff[t] = sb[t] - v;
    if (t == 0) { row_start[N_NODES] = N_EDGES; bstart[K_BKT] = N_EDGES; }
}

// within-block exclusive scan + block offset -> row_start; deg becomes per-node
// cursor; bucket-boundary nodes record bstart/bcursor.
__global__ __launch_bounds__(256) void blockscan_kernel(int* __restrict__ deg,
                                                        const int* __restrict__ boff,
                                                        int* __restrict__ row_start,
                                                        int* __restrict__ bstart,
                                                        int* __restrict__ bcursor) {
    __shared__ int sb[256];
    int t = threadIdx.x, i = blockIdx.x * 256 + t;
    int v = (i < N_NODES) ? deg[i] : 0;
    sb[t] = v;
    __syncthreads();
    for (int off = 1; off < 256; off <<= 1) {
        int add = (t >= off) ? sb[t - off] : 0;
        __syncthreads();
        sb[t] += add;
        __syncthreads();
    }
    if (i < N_NODES) {
        int excl = sb[t] - v + boff[blockIdx.x];
        row_start[i] = excl;
        deg[i] = excl;                      // per-node scatter cursor
        if (i % BKT_NODES == 0) {
            int b = i / BKT_NODES;
            bstart[b] = excl;
            bcursor[b] = excl;
        }
    }
}

// phase 1: bucket edges by dst range; wave-aggregated cursor atomics give
// dense contiguous 8B pair writes at the bucket's CSR base offset.
__global__ __launch_bounds__(256) void bucket_kernel(const int* __restrict__ src,
                                                     const int* __restrict__ dst,
                                                     int* __restrict__ bcursor,
                                                     uint2* __restrict__ staging) {
    int e = blockIdx.x * 256 + threadIdx.x;
    bool valid = e < N_EDGES;
    int s = 0, d = 0, b = -1;
    if (valid) { s = src[e]; d = dst[e]; b = d / BKT_NODES; }
    int lane = threadIdx.x & 63;
    unsigned long long lanebit = 1ull << lane;
    for (int bb = 0; bb < K_BKT; ++bb) {
        unsigned long long mask = __ballot(valid && b == bb);
        if (mask == 0ull) continue;                      // uniform
        int leader = __builtin_ctzll(mask);
        int base = 0;
        if (lane == leader) base = atomicAdd(&bcursor[bb], __popcll(mask));
        base = __shfl(base, leader);
        if (valid && b == bb) {
            int rank = __popcll(mask & (lanebit - 1ull));
            staging[base + rank] = make_uint2((unsigned)s, (unsigned)d);
        }
    }
}

// phase 2: per-bucket scatter into final CSR slots. Each bucket's target
// slice (~400KB edge_src + 25KB cursors) stays L2-resident.
__global__ __launch_bounds__(256) void scatter2_kernel(const uint2* __restrict__ staging,
                                                       const int* __restrict__ bstart,
                                                       int* __restrict__ cursor,
                                                       int* __restrict__ edge_src) {
    int b = blockIdx.x / BPB;
    int sub = blockIdx.x % BPB;
    int beg = bstart[b], end = bstart[b + 1];
    for (int i = beg + sub * 256 + threadIdx.x; i < end; i += BPB * 256) {
        uint2 p = staging[i];
        int pos = atomicAdd(&cursor[p.y], 1);
        edge_src[pos] = (int)p.x;
    }
}

// one wave per dst node; lane = channel; fp16 gathers (128B/row), batch-4
// online softmax, one 256B fp32 store per node, zero atomics.
__global__ __launch_bounds__(256) void fused_node_kernel(const __half* __restrict__ fth,
                                                         const int* __restrict__ row_start,
                                                         const int* __restrict__ edge_src,
                                                         float* __restrict__ out) {
    int wave = (blockIdx.x * 256 + threadIdx.x) >> 6;
    int lane = threadIdx.x & 63;
    if (wave >= N_NODES) return;

    int beg = row_start[wave];
    int end = row_start[wave + 1];
    float ftd = __half2float(fth[(size_t)wave * OUT_F + lane]);

    float m = -INFINITY, l = 0.f, acc = 0.f;
    int i = beg;
    for (; i + 4 <= end; i += 4) {
        int s0 = edge_src[i + 0], s1 = edge_src[i + 1];
        int s2 = edge_src[i + 2], s3 = edge_src[i + 3];
        float v0 = __half2float(fth[(size_t)s0 * OUT_F + lane]);
        float v1 = __half2float(fth[(size_t)s1 * OUT_F + lane]);
        float v2 = __half2float(fth[(size_t)s2 * OUT_F + lane]);
        float v3 = __half2float(fth[(size_t)s3 * OUT_F + lane]);
        float p0 = v0 * ftd, p1 = v1 * ftd, p2 = v2 * ftd, p3 = v3 * ftd;
#pragma unroll
        for (int d = 1; d < 64; d <<= 1) {
            p0 += __shfl_xor(p0, d);
            p1 += __shfl_xor(p1, d);
            p2 += __shfl_xor(p2, d);
            p3 += __shfl_xor(p3, d);
        }
        float bm = fmaxf(fmaxf(p0, p1), fmaxf(p2, p3));
        float nm = fmaxf(m, bm);
        float alpha = __expf(m - nm);          // exp(-inf)=0 first time
        float w0 = __expf(p0 - nm), w1 = __expf(p1 - nm);
        float w2 = __expf(p2 - nm), w3 = __expf(p3 - nm);
        l = l * alpha + ((w0 + w1) + (w2 + w3));
        acc = acc * alpha + ((w0 * v0 + w1 * v1) + (w2 * v2 + w3 * v3));
        m = nm;
    }
    for (; i < end; ++i) {
        int sN = edge_src[i];
        float v = __half2float(fth[(size_t)sN * OUT_F + lane]);
        float p = v * ftd;
#pragma unroll
        for (int d = 1; d < 64; d <<= 1) p += __shfl_xor(p, d);
        float nm = fmaxf(m, p);
        float alpha = __expf(m - nm);
        float w = __expf(p - nm);
        l = l * alpha + w;
        acc = acc * alpha + w * v;
        m = nm;
    }
    out[(size_t)wave * OUT_F + lane] = (l > 0.f) ? acc / l : 0.f;
}

extern "C" void kernel_launch(void* const* d_in, const int* in_sizes, int n_in,
                              void* d_out, int out_size, void* d_ws, size_t ws_size,
                              hipStream_t stream) {
    const float* feat = (const float*)d_in[0];
    const float* W    = (const float*)d_in[1];
    const int*   src  = (const int*)d_in[2];
    const int*   dst  = (const int*)d_in[3];
    float* out = (float*)d_out;

    __half* fth      = (__half*)d_ws;                                  // 3.2M u32
    uint2*  staging  = (uint2*)((int*)d_ws + (size_t)N_NODES * OUT_F / 2);
    int*    edge_src = (int*)(staging + N_EDGES);
    int*    deg      = edge_src + N_EDGES;
    int*    row_start= deg + N_NODES;
    int*    bsum     = row_start + N_NODES + 1;
    int*    boff     = bsum + NB;
    int*    bstart   = boff + NB;
    int*    bcursor  = bstart + K_BKT + 1;

    init_kernel<<<NB, 256, 0, stream>>>(deg);
    linear_count_kernel<<<NB + EB, 256, 0, stream>>>(feat, W, fth, dst, deg);
    blockreduce_kernel<<<NB, 256, 0, stream>>>(deg, bsum);
    scanbsum_kernel<<<1, 512, 0, stream>>>(bsum, boff, row_start, bstart);
    blockscan_kernel<<<NB, 256, 0, stream>>>(deg, boff, row_start, bstart, bcursor);
    bucket_kernel<<<EB, 256, 0, stream>>>(src, dst, bcursor, staging);
    scatter2_kernel<<<K_BKT * BPB, 256, 0, stream>>>(staging, bstart, deg, edge_src);
    fused_node_kernel<<<(N_NODES * 64 + 255) / 256, 256, 0, stream>>>(fth, row_start, edge_src, out);
}

// Round 5
// 355.938 us; speedup vs baseline: 13.7669x; 13.7669x over previous
//
#include <hip/hip_runtime.h>
#include <hip/hip_fp16.h>
#include <math.h>

#define N_NODES 100000
#define N_EDGES 1600000
#define IN_F    128
#define OUT_F   64
#define NB      ((N_NODES + 255) / 256)   // 391
#define EB      (N_EDGES / 256)           // 6250 (exact)
#define K_BKT     1000                    // dst-range buckets (node-aligned)
#define BKT_NODES 100                     // N_NODES / K_BKT exact
#define CHUNK     8192                    // edges per partition block
#define PBLKS   ((N_EDGES + CHUNK - 1) / CHUNK)   // 196

// ---------------- workspace layout (4-byte units) ----------------
// fth      : N_NODES*OUT_F/2  (fp16 projected features, 12.8 MB)
// staging  : N_EDGES uint2    (bucket-partitioned (src,dst), 12.8 MB)
// edge_src : N_EDGES          (final CSR src ids, 6.4 MB)
// deg      : N_NODES          (degree)
// row_start: N_NODES+1
// bsum/boff: NB each
// bcursor  : K_BKT            (partition reservation cursors)

__global__ __launch_bounds__(256) void init_kernel(int* __restrict__ deg) {
    int i = blockIdx.x * 256 + threadIdx.x;
    if (i < N_NODES) deg[i] = 0;
}

// blocks [0,NB): ft = feat @ W, stored fp16; blocks [NB,NB+EB): degree count
__global__ __launch_bounds__(256) void linear_count_kernel(const float* __restrict__ feat,
                                                           const float* __restrict__ W,
                                                           __half* __restrict__ fth,
                                                           const int* __restrict__ dst,
                                                           int* __restrict__ deg) {
    if (blockIdx.x >= NB) {
        int e = (blockIdx.x - NB) * 256 + threadIdx.x;
        if (e < N_EDGES) atomicAdd(&deg[dst[e]], 1);
        return;
    }
    __shared__ float4 Wl[IN_F * OUT_F / 4];   // 32 KB
    const float4* W4 = (const float4*)W;
    for (int i = threadIdx.x; i < IN_F * OUT_F / 4; i += 256) Wl[i] = W4[i];
    __syncthreads();

    int row = blockIdx.x * 256 + threadIdx.x;
    if (row >= N_NODES) return;
    const float4* fr = (const float4*)(feat + (size_t)row * IN_F);

    float acc[OUT_F];
#pragma unroll
    for (int c = 0; c < OUT_F; ++c) acc[c] = 0.f;

    for (int kc = 0; kc < IN_F / 4; ++kc) {
        float4 f = fr[kc];
        const float4* w0 = &Wl[(4 * kc + 0) * (OUT_F / 4)];
        const float4* w1 = &Wl[(4 * kc + 1) * (OUT_F / 4)];
        const float4* w2 = &Wl[(4 * kc + 2) * (OUT_F / 4)];
        const float4* w3 = &Wl[(4 * kc + 3) * (OUT_F / 4)];
#pragma unroll
        for (int c4 = 0; c4 < OUT_F / 4; ++c4) {
            float4 a0 = w0[c4], a1 = w1[c4], a2 = w2[c4], a3 = w3[c4];
            acc[4 * c4 + 0] += f.x * a0.x + f.y * a1.x + f.z * a2.x + f.w * a3.x;
            acc[4 * c4 + 1] += f.x * a0.y + f.y * a1.y + f.z * a2.y + f.w * a3.y;
            acc[4 * c4 + 2] += f.x * a0.z + f.y * a1.z + f.z * a2.z + f.w * a3.z;
            acc[4 * c4 + 3] += f.x * a0.w + f.y * a1.w + f.z * a2.w + f.w * a3.w;
        }
    }
    float4* o = (float4*)(fth + (size_t)row * OUT_F);
#pragma unroll
    for (int q = 0; q < 8; ++q) {
        unsigned u[4];
#pragma unroll
        for (int j = 0; j < 4; ++j) {
            int c = q * 8 + j * 2;
            __half h0 = __float2half_rn(acc[c]);
            __half h1 = __float2half_rn(acc[c + 1]);
            u[j] = (unsigned)__half_as_ushort(h0) | ((unsigned)__half_as_ushort(h1) << 16);
        }
        o[q] = make_float4(__uint_as_float(u[0]), __uint_as_float(u[1]),
                           __uint_as_float(u[2]), __uint_as_float(u[3]));
    }
}

__global__ __launch_bounds__(256) void blockreduce_kernel(const int* __restrict__ deg,
                                                          int* __restrict__ bsum) {
    __shared__ int sb[256];
    int t = threadIdx.x, i = blockIdx.x * 256 + t;
    sb[t] = (i < N_NODES) ? deg[i] : 0;
    __syncthreads();
    for (int off = 128; off > 0; off >>= 1) {
        if (t < off) sb[t] += sb[t + off];
        __syncthreads();
    }
    if (t == 0) bsum[blockIdx.x] = sb[0];
}

__global__ __launch_bounds__(512) void scanbsum_kernel(const int* __restrict__ bsum,
                                                       int* __restrict__ boff,
                                                       int* __restrict__ row_start) {
    __shared__ int sb[512];
    int t = threadIdx.x;
    int v = (t < NB) ? bsum[t] : 0;
    sb[t] = v;
    __syncthreads();
    for (int off = 1; off < 512; off <<= 1) {
        int add = (t >= off) ? sb[t - off] : 0;
        __syncthreads();
        sb[t] += add;
        __syncthreads();
    }
    if (t < NB) boff[t] = sb[t] - v;
    if (t == 0) row_start[N_NODES] = N_EDGES;
}

// exclusive scan -> row_start; bucket-boundary nodes init partition cursors
__global__ __launch_bounds__(256) void blockscan_kernel(const int* __restrict__ deg,
                                                        const int* __restrict__ boff,
                                                        int* __restrict__ row_start,
                                                        int* __restrict__ bcursor) {
    __shared__ int sb[256];
    int t = threadIdx.x, i = blockIdx.x * 256 + t;
    int v = (i < N_NODES) ? deg[i] : 0;
    sb[t] = v;
    __syncthreads();
    for (int off = 1; off < 256; off <<= 1) {
        int add = (t >= off) ? sb[t - off] : 0;
        __syncthreads();
        sb[t] += add;
        __syncthreads();
    }
    if (i < N_NODES) {
        int excl = sb[t] - v + boff[blockIdx.x];
        row_start[i] = excl;
        if (i % BKT_NODES == 0) bcursor[i / BKT_NODES] = excl;
    }
}

// radix-lite partition: per-block LDS histogram over 1000 node-aligned
// buckets, one global reservation per (block,bucket), dense staged writes.
// No hot counters: <=196 atomics per bucket line, spread over 4 KB.
__global__ __launch_bounds__(256) void partition_kernel(const int* __restrict__ src,
                                                        const int* __restrict__ dst,
                                                        int* __restrict__ bcursor,
                                                        uint2* __restrict__ staging) {
    __shared__ int hist[K_BKT];
    __shared__ int base[K_BKT];
    int t = threadIdx.x;
    for (int i = t; i < K_BKT; i += 256) hist[i] = 0;
    __syncthreads();
    int beg = blockIdx.x * CHUNK;
    int end = min(beg + CHUNK, N_EDGES);
    for (int i = beg + t; i < end; i += 256)
        atomicAdd(&hist[dst[i] / BKT_NODES], 1);
    __syncthreads();
    for (int i = t; i < K_BKT; i += 256) {
        int h = hist[i];
        base[i] = h ? atomicAdd(&bcursor[i], h) : 0;
        hist[i] = 0;   // reuse as within-block rank counter
    }
    __syncthreads();
    for (int i = beg + t; i < end; i += 256) {
        int s = src[i], d = dst[i];
        int b = d / BKT_NODES;
        int r = atomicAdd(&hist[b], 1);
        staging[base[b] + r] = make_uint2((unsigned)s, (unsigned)d);
    }
}

// one block per bucket: place staged edges into exact CSR slots via LDS
// per-node cursors. All writes to a bucket's CSR slice come from ONE block
// (one XCD) -> full dirty lines, no cross-XCD write amplification.
__global__ __launch_bounds__(256) void place_kernel(const uint2* __restrict__ staging,
                                                    const int* __restrict__ row_start,
                                                    int* __restrict__ edge_src) {
    __shared__ int lcur[BKT_NODES];
    int node0 = blockIdx.x * BKT_NODES;
    int t = threadIdx.x;
    if (t < BKT_NODES) lcur[t] = row_start[node0 + t];
    __syncthreads();
    int beg = row_start[node0];
    int end = row_start[node0 + BKT_NODES];
    for (int i = beg + t; i < end; i += 256) {
        uint2 p = staging[i];
        int pos = atomicAdd(&lcur[(int)p.y - node0], 1);
        edge_src[pos] = (int)p.x;
    }
}

// one wave per dst node; lane = channel; fp16 gathers (128B/row), batch-4
// online softmax, one 256B fp32 store per node, zero atomics.
__global__ __launch_bounds__(256) void fused_node_kernel(const __half* __restrict__ fth,
                                                         const int* __restrict__ row_start,
                                                         const int* __restrict__ edge_src,
                                                         float* __restrict__ out) {
    int wave = (blockIdx.x * 256 + threadIdx.x) >> 6;
    int lane = threadIdx.x & 63;
    if (wave >= N_NODES) return;

    int beg = row_start[wave];
    int end = row_start[wave + 1];
    float ftd = __half2float(fth[(size_t)wave * OUT_F + lane]);

    float m = -INFINITY, l = 0.f, acc = 0.f;
    int i = beg;
    for (; i + 4 <= end; i += 4) {
        int s0 = edge_src[i + 0], s1 = edge_src[i + 1];
        int s2 = edge_src[i + 2], s3 = edge_src[i + 3];
        float v0 = __half2float(fth[(size_t)s0 * OUT_F + lane]);
        float v1 = __half2float(fth[(size_t)s1 * OUT_F + lane]);
        float v2 = __half2float(fth[(size_t)s2 * OUT_F + lane]);
        float v3 = __half2float(fth[(size_t)s3 * OUT_F + lane]);
        float p0 = v0 * ftd, p1 = v1 * ftd, p2 = v2 * ftd, p3 = v3 * ftd;
#pragma unroll
        for (int d = 1; d < 64; d <<= 1) {
            p0 += __shfl_xor(p0, d);
            p1 += __shfl_xor(p1, d);
            p2 += __shfl_xor(p2, d);
            p3 += __shfl_xor(p3, d);
        }
        float bm = fmaxf(fmaxf(p0, p1), fmaxf(p2, p3));
        float nm = fmaxf(m, bm);
        float alpha = __expf(m - nm);          // exp(-inf)=0 first time
        float w0 = __expf(p0 - nm), w1 = __expf(p1 - nm);
        float w2 = __expf(p2 - nm), w3 = __expf(p3 - nm);
        l = l * alpha + ((w0 + w1) + (w2 + w3));
        acc = acc * alpha + ((w0 * v0 + w1 * v1) + (w2 * v2 + w3 * v3));
        m = nm;
    }
    for (; i < end; ++i) {
        int sN = edge_src[i];
        float v = __half2float(fth[(size_t)sN * OUT_F + lane]);
        float p = v * ftd;
#pragma unroll
        for (int d = 1; d < 64; d <<= 1) p += __shfl_xor(p, d);
        float nm = fmaxf(m, p);
        float alpha = __expf(m - nm);
        float w = __expf(p - nm);
        l = l * alpha + w;
        acc = acc * alpha + w * v;
        m = nm;
    }
    out[(size_t)wave * OUT_F + lane] = (l > 0.f) ? acc / l : 0.f;
}

extern "C" void kernel_launch(void* const* d_in, const int* in_sizes, int n_in,
                              void* d_out, int out_size, void* d_ws, size_t ws_size,
                              hipStream_t stream) {
    const float* feat = (const float*)d_in[0];
    const float* W    = (const float*)d_in[1];
    const int*   src  = (const int*)d_in[2];
    const int*   dst  = (const int*)d_in[3];
    float* out = (float*)d_out;

    __half* fth      = (__half*)d_ws;
    uint2*  staging  = (uint2*)((int*)d_ws + (size_t)N_NODES * OUT_F / 2);
    int*    edge_src = (int*)(staging + N_EDGES);
    int*    deg      = edge_src + N_EDGES;
    int*    row_start= deg + N_NODES;
    int*    bsum     = row_start + N_NODES + 1;
    int*    boff     = bsum + NB;
    int*    bcursor  = boff + NB;

    init_kernel<<<NB, 256, 0, stream>>>(deg);
    linear_count_kernel<<<NB + EB, 256, 0, stream>>>(feat, W, fth, dst, deg);
    blockreduce_kernel<<<NB, 256, 0, stream>>>(deg, bsum);
    scanbsum_kernel<<<1, 512, 0, stream>>>(bsum, boff, row_start);
    blockscan_kernel<<<NB, 256, 0, stream>>>(deg, boff, row_start, bcursor);
    partition_kernel<<<PBLKS, 256, 0, stream>>>(src, dst, bcursor, staging);
    place_kernel<<<K_BKT, 256, 0, stream>>>(staging, row_start, edge_src);
    fused_node_kernel<<<(N_NODES * 64 + 255) / 256, 256, 0, stream>>>(fth, row_start, edge_src, out);
}

// Round 6
// 256.848 us; speedup vs baseline: 19.0781x; 1.3858x over previous
//
#include <hip/hip_runtime.h>
#include <hip/hip_fp16.h>
#include <math.h>

#define N_NODES 100000
#define N_EDGES 1600000
#define IN_F    128
#define OUT_F   64
#define NB      ((N_NODES + 255) / 256)   // 391 linear blocks
#define K_BKT     1000                    // dst-range buckets (node-aligned)
#define BKT_NODES 100                     // N_NODES / K_BKT exact
#define CHUNK     8192                    // edges per counting/partition block
#define PBLKS   ((N_EDGES + CHUNK - 1) / CHUNK)   // 196

// ---------------- workspace layout (4-byte units) ----------------
// fth          : N_NODES*OUT_F/2  (fp16 projected features, 12.8 MB)
// mat          : PBLKS*K_BKT      (per-(block,bucket) counts -> write bases)
// staging      : N_EDGES uint     (packed src|dloc<<17, 6.4 MB)
// edge_src     : N_EDGES          (final CSR src ids)
// bucket_start : K_BKT+1
// row_start    : N_NODES+1

// per-chunk histogram over 1000 buckets -> count matrix row (no atomics)
__global__ __launch_bounds__(256) void bucket_count_kernel(const int* __restrict__ dst,
                                                           int* __restrict__ mat) {
    __shared__ int hist[K_BKT];
    int t = threadIdx.x;
    for (int j = t; j < K_BKT; j += 256) hist[j] = 0;
    __syncthreads();
    int beg = blockIdx.x * CHUNK;
    int end = min(beg + CHUNK, N_EDGES);
    for (int i = beg + t; i < end; i += 256)
        atomicAdd(&hist[dst[i] / BKT_NODES], 1);
    __syncthreads();
    for (int j = t; j < K_BKT; j += 256) mat[blockIdx.x * K_BKT + j] = hist[j];
}

// bucket totals -> exclusive scan -> bucket_start; transform mat in place to
// exact per-(block,bucket) staging bases (column-wise exclusive prefix).
__global__ __launch_bounds__(1024) void scan_kernel(int* __restrict__ mat,
                                                    int* __restrict__ bucket_start,
                                                    int* __restrict__ row_start) {
    __shared__ int sb[1024];
    int t = threadIdx.x;
    int tot = 0;
    if (t < K_BKT)
        for (int k = 0; k < PBLKS; ++k) tot += mat[k * K_BKT + t];
    sb[t] = tot;
    __syncthreads();
    for (int off = 1; off < 1024; off <<= 1) {
        int add = (t >= off) ? sb[t - off] : 0;
        __syncthreads();
        sb[t] += add;
        __syncthreads();
    }
    if (t < K_BKT) {
        int run = sb[t] - tot;           // exclusive
        bucket_start[t] = run;
        for (int k = 0; k < PBLKS; ++k) {
            int old = mat[k * K_BKT + t];
            mat[k * K_BKT + t] = run;
            run += old;
        }
    }
    if (t == 0) { bucket_start[K_BKT] = N_EDGES; row_start[N_NODES] = N_EDGES; }
}

// blocks [0,PBLKS): partition edges into bucket-dense staging (LDS ranks,
// precomputed bases -> zero global atomics). blocks [PBLKS,..): ft = feat@W.
__global__ __launch_bounds__(256) void partition_linear_kernel(const float* __restrict__ feat,
                                                               const float* __restrict__ W,
                                                               __half* __restrict__ fth,
                                                               const int* __restrict__ src,
                                                               const int* __restrict__ dst,
                                                               const int* __restrict__ mat,
                                                               unsigned* __restrict__ staging) {
    __shared__ alignas(16) unsigned char smem[32768];
    int t = threadIdx.x;
    if (blockIdx.x < PBLKS) {
        int* hist  = (int*)smem;          // 1000
        int* basep = hist + K_BKT;        // 1000
        for (int j = t; j < K_BKT; j += 256) {
            hist[j] = 0;
            basep[j] = mat[blockIdx.x * K_BKT + j];
        }
        __syncthreads();
        int beg = blockIdx.x * CHUNK;
        int end = min(beg + CHUNK, N_EDGES);
        for (int i = beg + t; i < end; i += 256) {
            int s = src[i], d = dst[i];
            int b = d / BKT_NODES;
            int r = atomicAdd(&hist[b], 1);
            staging[basep[b] + r] = (unsigned)s | ((unsigned)(d - b * BKT_NODES) << 17);
        }
        return;
    }
    // ---- linear part ----
    float4* Wl = (float4*)smem;           // 2048 float4 = 32 KB
    const float4* W4 = (const float4*)W;
    for (int i = t; i < IN_F * OUT_F / 4; i += 256) Wl[i] = W4[i];
    __syncthreads();

    int row = (blockIdx.x - PBLKS) * 256 + t;
    if (row >= N_NODES) return;
    const float4* fr = (const float4*)(feat + (size_t)row * IN_F);

    float acc[OUT_F];
#pragma unroll
    for (int c = 0; c < OUT_F; ++c) acc[c] = 0.f;

    for (int kc = 0; kc < IN_F / 4; ++kc) {
        float4 f = fr[kc];
        const float4* w0 = &Wl[(4 * kc + 0) * (OUT_F / 4)];
        const float4* w1 = &Wl[(4 * kc + 1) * (OUT_F / 4)];
        const float4* w2 = &Wl[(4 * kc + 2) * (OUT_F / 4)];
        const float4* w3 = &Wl[(4 * kc + 3) * (OUT_F / 4)];
#pragma unroll
        for (int c4 = 0; c4 < OUT_F / 4; ++c4) {
            float4 a0 = w0[c4], a1 = w1[c4], a2 = w2[c4], a3 = w3[c4];
            acc[4 * c4 + 0] += f.x * a0.x + f.y * a1.x + f.z * a2.x + f.w * a3.x;
            acc[4 * c4 + 1] += f.x * a0.y + f.y * a1.y + f.z * a2.y + f.w * a3.y;
            acc[4 * c4 + 2] += f.x * a0.z + f.y * a1.z + f.z * a2.z + f.w * a3.z;
            acc[4 * c4 + 3] += f.x * a0.w + f.y * a1.w + f.z * a2.w + f.w * a3.w;
        }
    }
    float4* o = (float4*)(fth + (size_t)row * OUT_F);
#pragma unroll
    for (int q = 0; q < 8; ++q) {
        unsigned u[4];
#pragma unroll
        for (int j = 0; j < 4; ++j) {
            int c = q * 8 + j * 2;
            __half h0 = __float2half_rn(acc[c]);
            __half h1 = __float2half_rn(acc[c + 1]);
            u[j] = (unsigned)__half_as_ushort(h0) | ((unsigned)__half_as_ushort(h1) << 16);
        }
        o[q] = make_float4(__uint_as_float(u[0]), __uint_as_float(u[1]),
                           __uint_as_float(u[2]), __uint_as_float(u[3]));
    }
}

// one block per bucket: derive per-node degrees + row_start (LDS hist+scan),
// then place src ids into exact CSR slots. One block -> one XCD -> full lines.
__global__ __launch_bounds__(256) void place_kernel(const unsigned* __restrict__ staging,
                                                    const int* __restrict__ bucket_start,
                                                    int* __restrict__ row_start,
                                                    int* __restrict__ edge_src) {
    __shared__ int cnt[BKT_NODES];
    __shared__ int sc[128];
    __shared__ int lcur[BKT_NODES];
    int t = threadIdx.x;
    if (t < BKT_NODES) cnt[t] = 0;
    __syncthreads();
    int base = bucket_start[blockIdx.x];
    int end  = bucket_start[blockIdx.x + 1];
    for (int i = base + t; i < end; i += 256)
        atomicAdd(&cnt[staging[i] >> 17], 1);
    __syncthreads();
    int v = (t < BKT_NODES) ? cnt[t] : 0;
    if (t < 128) sc[t] = v;
    __syncthreads();
    for (int off = 1; off < 128; off <<= 1) {
        int add = (t < 128 && t >= off) ? sc[t - off] : 0;
        __syncthreads();
        if (t < 128) sc[t] += add;
        __syncthreads();
    }
    if (t < BKT_NODES) {
        int excl = base + sc[t] - v;
        lcur[t] = excl;
        row_start[blockIdx.x * BKT_NODES + t] = excl;
    }
    __syncthreads();
    for (int i = base + t; i < end; i += 256) {
        unsigned u = staging[i];
        int pos = atomicAdd(&lcur[u >> 17], 1);
        edge_src[pos] = (int)(u & 0x1FFFFu);
    }
}

// one wave per dst node. 16 lanes/edge (4 channels/lane, 8B loads), 4 edges
// in flight per wave, reduce depth 4; quarter-states merged once at the end.
__global__ __launch_bounds__(256) void fused_node_kernel(const __half* __restrict__ fth,
                                                         const int* __restrict__ row_start,
                                                         const int* __restrict__ edge_src,
                                                         float* __restrict__ out) {
    int wave = (blockIdx.x * 256 + threadIdx.x) >> 6;
    int lane = threadIdx.x & 63;
    if (wave >= N_NODES) return;
    int q = lane >> 4, ql = lane & 15;

    int beg = row_start[wave];
    int end = row_start[wave + 1];

    float2 rd = *(const float2*)(fth + (size_t)wave * OUT_F + 4 * ql);
    __half2 d01 = *(__half2*)&rd.x, d23 = *(__half2*)&rd.y;
    float fd0 = __half2float(d01.x), fd1 = __half2float(d01.y);
    float fd2 = __half2float(d23.x), fd3 = __half2float(d23.y);

    float m = -1e30f, l = 0.f;
    float a0 = 0.f, a1 = 0.f, a2 = 0.f, a3 = 0.f;

    for (int i = beg; i < end; i += 8) {
        int eA = i + q, eB = i + 4 + q;
        bool vA = eA < end, vB = eB < end;
        int sA = edge_src[vA ? eA : (end - 1)];
        int sB = edge_src[vB ? eB : (end - 1)];
        float2 rA = *(const float2*)(fth + (size_t)sA * OUT_F + 4 * ql);
        float2 rB = *(const float2*)(fth + (size_t)sB * OUT_F + 4 * ql);
        __half2 A01 = *(__half2*)&rA.x, A23 = *(__half2*)&rA.y;
        __half2 B01 = *(__half2*)&rB.x, B23 = *(__half2*)&rB.y;
        float vA0 = __half2float(A01.x), vA1 = __half2float(A01.y);
        float vA2 = __half2float(A23.x), vA3 = __half2float(A23.y);
        float vB0 = __half2float(B01.x), vB1 = __half2float(B01.y);
        float vB2 = __half2float(B23.x), vB3 = __half2float(B23.y);

        float pA = vA0 * fd0 + vA1 * fd1 + vA2 * fd2 + vA3 * fd3;
        float pB = vB0 * fd0 + vB1 * fd1 + vB2 * fd2 + vB3 * fd3;
#pragma unroll
        for (int d = 1; d < 16; d <<= 1) {
            pA += __shfl_xor(pA, d);
            pB += __shfl_xor(pB, d);
        }
        if (!vA) pA = -1e30f;
        if (!vB) pB = -1e30f;
        float nm = fmaxf(fmaxf(m, pA), pB);
        float alpha = __expf(m - nm);      // m=nm=-1e30 -> 1, harmless (l=0)
        float wA = vA ? __expf(pA - nm) : 0.f;
        float wB = vB ? __expf(pB - nm) : 0.f;
        l = l * alpha + (wA + wB);
        a0 = a0 * alpha + wA * vA0 + wB * vB0;
        a1 = a1 * alpha + wA * vA1 + wB * vB1;
        a2 = a2 * alpha + wA * vA2 + wB * vB2;
        a3 = a3 * alpha + wA * vA3 + wB * vB3;
        m = nm;
    }

    // merge the 4 quarter-states (xor16, then xor32)
#pragma unroll
    for (int d = 16; d <= 32; d <<= 1) {
        float m2 = __shfl_xor(m, d), l2 = __shfl_xor(l, d);
        float b0 = __shfl_xor(a0, d), b1 = __shfl_xor(a1, d);
        float b2 = __shfl_xor(a2, d), b3 = __shfl_xor(a3, d);
        float M = fmaxf(m, m2);
        float e1 = __expf(m - M), e2 = __expf(m2 - M);
        l = l * e1 + l2 * e2;
        a0 = a0 * e1 + b0 * e2;
        a1 = a1 * e1 + b1 * e2;
        a2 = a2 * e1 + b2 * e2;
        a3 = a3 * e1 + b3 * e2;
        m = M;
    }
    if (q == 0) {
        float inv = (l > 0.f) ? 1.f / l : 0.f;
        *(float4*)(out + (size_t)wave * OUT_F + 4 * ql) =
            make_float4(a0 * inv, a1 * inv, a2 * inv, a3 * inv);
    }
}

extern "C" void kernel_launch(void* const* d_in, const int* in_sizes, int n_in,
                              void* d_out, int out_size, void* d_ws, size_t ws_size,
                              hipStream_t stream) {
    const float* feat = (const float*)d_in[0];
    const float* W    = (const float*)d_in[1];
    const int*   src  = (const int*)d_in[2];
    const int*   dst  = (const int*)d_in[3];
    float* out = (float*)d_out;

    __half*   fth          = (__half*)d_ws;
    int*      mat          = (int*)d_ws + (size_t)N_NODES * OUT_F / 2;
    unsigned* staging      = (unsigned*)(mat + PBLKS * K_BKT);
    int*      edge_src     = (int*)(staging + N_EDGES);
    int*      bucket_start = edge_src + N_EDGES;
    int*      row_start    = bucket_start + K_BKT + 1;

    bucket_count_kernel<<<PBLKS, 256, 0, stream>>>(dst, mat);
    scan_kernel<<<1, 1024, 0, stream>>>(mat, bucket_start, row_start);
    partition_linear_kernel<<<PBLKS + NB, 256, 0, stream>>>(feat, W, fth, src, dst, mat, staging);
    place_kernel<<<K_BKT, 256, 0, stream>>>(staging, bucket_start, row_start, edge_src);
    fused_node_kernel<<<(N_NODES * 64) / 256, 256, 0, stream>>>(fth, row_start, edge_src, out);
}